// Round 10
// baseline (298.414 us; speedup 1.0000x reference)
//
#include <hip/hip_runtime.h>

#define NN 10000
#define BB 8
#define EE 160000
#define DH 128
#define LN_EPS 1e-5f

typedef unsigned short ushort_t;
typedef unsigned int uint_t;

typedef __bf16 bf16x8 __attribute__((ext_vector_type(8)));
typedef float floatx4 __attribute__((ext_vector_type(4)));
typedef float floatx2 __attribute__((ext_vector_type(2)));

__device__ __forceinline__ float b2f(uint_t u) { return __uint_as_float(u << 16); }
__device__ __forceinline__ ushort_t f2b(float f) {
    uint_t u = __float_as_uint(f);
    return (ushort_t)((u + 0x7fffu + ((u >> 16) & 1u)) >> 16);
}
__device__ __forceinline__ uint_t pack2(float lo, float hi) {
    return (uint_t)f2b(lo) | ((uint_t)f2b(hi) << 16);
}
__device__ __forceinline__ float sigm(float x) { return 1.0f / (1.0f + __expf(-x)); }
__device__ __forceinline__ float tanh_fast(float x) {
    float ex = __expf(2.0f * x);
    return 1.0f - 2.0f / (ex + 1.0f);
}

// unpack u32 holding 2 bf16 -> float2
__device__ __forceinline__ floatx2 unpk(uint_t u) {
    floatx2 r;
    r.x = __uint_as_float(u << 16);
    r.y = __uint_as_float(u & 0xffff0000u);
    return r;
}
// packed dual-FMA: a += w * v  (one VALU inst per 2 floats)
__device__ __forceinline__ void pk_fma(floatx2& a, floatx2 w, floatx2 v) {
    asm("v_pk_fma_f32 %0, %1, %2, %0" : "+v"(a) : "v"(w), "v"(v));
}
// accumulate 8 bf16 (uint4) with packed weight w2: 8 unpack + 4 pk_fma
__device__ __forceinline__ void acc8p(floatx2* a, floatx2 w2, uint4 v) {
    pk_fma(a[0], w2, unpk(v.x));
    pk_fma(a[1], w2, unpk(v.y));
    pk_fma(a[2], w2, unpk(v.z));
    pk_fma(a[3], w2, unpk(v.w));
}

// ---------------- CSR build ----------------

__global__ __launch_bounds__(256) void scan1(const int* __restrict__ cnt,
                                             int* __restrict__ offs,
                                             int* __restrict__ bsum) {
    __shared__ int s[256];
    const int t = threadIdx.x, idx = blockIdx.x * 256 + t;
    int x = (idx < NN) ? cnt[idx] : 0;
    s[t] = x;
    __syncthreads();
    for (int o = 1; o < 256; o <<= 1) {
        int v = s[t];
        int u = (t >= o) ? s[t - o] : 0;
        __syncthreads();
        s[t] = v + u;
        __syncthreads();
    }
    if (idx < NN) offs[idx] = s[t] - x;  // block-local exclusive
    if (t == 255) bsum[blockIdx.x] = s[255];
}

// scan3 also does the cross-block prefix (scan2 fused away)
__global__ __launch_bounds__(256) void scan3(const int* __restrict__ cnt,
                                             const int* __restrict__ bsum,
                                             int* __restrict__ offs,
                                             int* __restrict__ cursor,
                                             float* __restrict__ dis) {
    __shared__ int sb[40];
    __shared__ int pfx;
    const int t = threadIdx.x;
    if (t < 40) sb[t] = bsum[t];
    __syncthreads();
    if (t == 0) {
        int a = 0;
        for (int i = 0; i < blockIdx.x; ++i) a += sb[i];
        pfx = a;
    }
    __syncthreads();
    const int idx = blockIdx.x * 256 + t;
    if (idx < NN) {
        int off = offs[idx] + pfx;
        offs[idx] = off;
        cursor[idx] = off;
        dis[idx] = rsqrtf((float)(cnt[idx] + 1));
    }
    if (idx == 0) offs[NN] = EE;
}

// csr packed: bf16(dis[src])<<16 | src   (src < 16384 fits 14 bits)
__global__ void fill_csr(const int* __restrict__ ei, int* __restrict__ cursor,
                         const float* __restrict__ dis, int* __restrict__ csr_pk) {
    int e = blockIdx.x * 256 + threadIdx.x;
    if (e < EE) {
        int s = ei[e];
        int d = ei[EE + e];
        int pos = atomicAdd(&cursor[d], 1);
        csr_pk[pos] = (int)(((uint_t)f2b(dis[s]) << 16) | (uint_t)s);
    }
}

// ---------------- merged: count_deg | pack x,h interleaved + Wt transpose ---------
// xhb layout: [b*NN+n][256] with x in cols 0..127, h in cols 128..255.
// A wave's 64 lanes write one fully contiguous 1 KB span (two 512 B rows).

__global__ __launch_bounds__(256) void cp_k(const int* __restrict__ ei,
                                            int* __restrict__ cnt,
                                            const float* __restrict__ x,
                                            const float* __restrict__ h,
                                            ushort_t* __restrict__ xhb,
                                            const float* __restrict__ Wz,
                                            const float* __restrict__ Wr,
                                            const float* __restrict__ Wc,
                                            ushort_t* __restrict__ Wt_zr,
                                            ushort_t* __restrict__ Wt_c) {
    if (blockIdx.x < 625) {  // count_deg: 625*256 = 160000 = EE
        int e = blockIdx.x * 256 + threadIdx.x;
        atomicAdd(&cnt[ei[EE + e]], 1);
        return;
    }
    const int bid = blockIdx.x - 625;
    if (bid < 10000) {
        const size_t o = ((size_t)bid * 256 + threadIdx.x) * 4;  // elem idx in [0,10.24M)
        const size_t row = o >> 7, col = o & 127;
        float4 vx = *(const float4*)(x + o);
        uint2 px;
        px.x = pack2(vx.x, vx.y);
        px.y = pack2(vx.z, vx.w);
        *(uint2*)(xhb + row * 256 + col) = px;
        float4 vh = *(const float4*)(h + o);
        uint2 ph;
        ph.x = pack2(vh.x, vh.y);
        ph.y = pack2(vh.z, vh.w);
        *(uint2*)(xhb + row * 256 + 128 + col) = ph;
    } else {
        const int col = bid - 10000, k = threadIdx.x;
        if (col < 256) {
            float v = (col < 128) ? Wz[(size_t)k * 128 + col]
                                  : Wr[(size_t)k * 128 + col - 128];
            Wt_zr[(size_t)col * 256 + k] = f2b(v);
        } else {
            int c2 = col - 256;
            Wt_c[(size_t)c2 * 256 + k] = f2b(Wc[(size_t)k * 128 + c2]);
        }
    }
}

// ---------------- gather16: 4 waves x 4 nodes/wave, 16 lanes per node -------------
// dst[b,n] = dis[n] * ( sum_e dis[s]*src[b,s] + dis[n]*src[b,n] )
// MODE 0 (xh pass): src = xhb [b][n][256]; one addr per edge serves BOTH halves
// (h-load = x-load + 128, folded into the load's immediate offset). Writes both
// halves of agg_xh. MODE 1 (rh pass): src = rh_bf [b][n][128]; writes only the
// h-half of agg_xh (cols 128..255), preserving the x-half for the second GEMM.
// b = blockIdx&7 keeps XCD/L2 batch sharding. Packed CSR word -> ONE bpermute
// per edge; junk slots broadcast 0 -> weight 0.0 -> no predication.

template <int MODE>
__global__ __launch_bounds__(256) void gather16(
    const ushort_t* __restrict__ src, const int* __restrict__ offs,
    const int* __restrict__ csr_pk, const float* __restrict__ dis,
    ushort_t* __restrict__ dst) {
    const int tid = threadIdx.x, lane = tid & 63;
    const int b = blockIdx.x & 7;
    const int g = lane >> 4, il = lane & 15;
    const int ng = (blockIdx.x >> 3) * 16 + (tid >> 6) * 4 + g;  // my group's node
    const uint_t SST = (MODE == 0) ? 256u : 128u;
    const ushort_t* base = src + (size_t)b * NN * SST;
    const uint_t cofs = (uint_t)il * 8u;

    floatx2 a0[4], a1[4];
#pragma unroll
    for (int j = 0; j < 4; ++j) {
        a0[j] = (floatx2){0.f, 0.f};
        a1[j] = (floatx2){0.f, 0.f};
    }

    const int e0 = offs[ng], e1 = offs[ng + 1];
    const float dn = dis[ng];

    {  // self row, weight dn inside the sum
        const floatx2 d2 = {dn, dn};
        const uint_t off = (uint_t)ng * SST + cofs;
        acc8p(a0, d2, *(const uint4*)(base + off));
        if (MODE == 0) acc8p(a1, d2, *(const uint4*)(base + off + 128));
    }

    // max degree over the wave's 4 groups -> uniform loop bound
    int mx = e1 - e0;
    mx = max(mx, __shfl_xor(mx, 16));
    mx = max(mx, __shfl_xor(mx, 32));
    const int dmax = __builtin_amdgcn_readfirstlane(mx);
    const int pbase = (lane & 48) << 2;  // bpermute byte base of group's lane 0

    for (int ibase = 0; ibase < dmax; ibase += 16) {
        // refill: lane il of group g holds packed edge e0+ibase+il (0 if past end)
        int pk = 0;
        const int pos = e0 + ibase + il;
        if (pos < e1) pk = csr_pk[pos];
        const int lim = (dmax - ibase) < 16 ? (dmax - ibase) : 16;

        // 8 edges per step: all metadata, then all loads, then all FMAs
#define PROC8(OFF)                                                                   \
    {                                                                                \
        int p[8];                                                                    \
        uint_t q[8];                                                                 \
        _Pragma("unroll") for (int k = 0; k < 8; ++k) p[k] =                         \
            __builtin_amdgcn_ds_bpermute(pbase + ((OFF) + k) * 4, pk);               \
        _Pragma("unroll") for (int k = 0; k < 8; ++k) q[k] =                         \
            (uint_t)(p[k] & 0xffff) * SST + cofs;                                    \
        uint4 v[8];                                                                  \
        _Pragma("unroll") for (int k = 0; k < 8; ++k) v[k] =                         \
            *(const uint4*)(base + q[k]);                                            \
        uint4 u[8];                                                                  \
        if (MODE == 0) {                                                             \
            _Pragma("unroll") for (int k = 0; k < 8; ++k) u[k] =                     \
                *(const uint4*)(base + q[k] + 128);                                  \
        }                                                                            \
        _Pragma("unroll") for (int k = 0; k < 8; ++k) {                              \
            const float f = __uint_as_float((uint_t)p[k] & 0xffff0000u);             \
            const floatx2 w2 = {f, f};                                               \
            acc8p(a0, w2, v[k]);                                                     \
            if (MODE == 0) acc8p(a1, w2, u[k]);                                      \
        }                                                                            \
    }
        PROC8(0);
        if (lim > 8) PROC8(8);
#undef PROC8
    }

    // lane-private result: scale by dn, pack, store (all 64 lanes)
    const size_t o = ((size_t)b * NN + ng) * 256 + cofs;
    uint4 st;
    st.x = pack2(a0[0].x * dn, a0[0].y * dn);
    st.y = pack2(a0[1].x * dn, a0[1].y * dn);
    st.z = pack2(a0[2].x * dn, a0[2].y * dn);
    st.w = pack2(a0[3].x * dn, a0[3].y * dn);
    if (MODE == 0) {
        *(uint4*)(dst + o) = st;  // x-half
        uint4 st1;
        st1.x = pack2(a1[0].x * dn, a1[0].y * dn);
        st1.y = pack2(a1[1].x * dn, a1[1].y * dn);
        st1.z = pack2(a1[2].x * dn, a1[2].y * dn);
        st1.w = pack2(a1[3].x * dn, a1[3].y * dn);
        *(uint4*)(dst + o + 128) = st1;  // h-half
    } else {
        *(uint4*)(dst + o + 128) = st;  // rh into h-half, x-half preserved
    }
}

// ---------------- gemm_zr: 128x256 tile, K=256, z|r fused, one A pass -------------
// A = agg_xh [80000][256]; B = Wt_zr [256 outcols][256]. 512 threads / 8 waves,
// wave owns 16 rows x 256 cols (16 accs). Register-prefetch pipeline as gemm_c.
// Epilogue: cols 0..127 -> z = sigmoid -> z_buf bf16; cols 128..255 -> r = sigmoid,
// rh = r*h_prev -> rh_bf bf16.

__global__ __launch_bounds__(512) void gemm_zr(
    const ushort_t* __restrict__ A, const ushort_t* __restrict__ Wt,
    const float* __restrict__ bz, const float* __restrict__ br,
    const float* __restrict__ h_prev, ushort_t* __restrict__ z_out,
    ushort_t* __restrict__ rh_out) {
    __shared__ __align__(16) ushort_t As[128 * 72];
    __shared__ __align__(16) ushort_t Bs[256 * 72];
    const int tid = threadIdx.x;
    const int rb0 = blockIdx.x * 128;
    const int wv = tid >> 6, lane = tid & 63;
    const int l15 = lane & 15, qq = lane >> 4;
    const int sr = tid >> 2;        // 0..127: A row staged by this thread
    const int kh = (tid & 3) * 16;  // A: 16-elem K chunk
    const int sc = tid >> 1;        // 0..255: B col staged by this thread
    const int kb = (tid & 1) * 32;  // B: 32-elem K chunk

    floatx4 acc[16];
#pragma unroll
    for (int j = 0; j < 16; ++j) acc[j] = (floatx4){0.f, 0.f, 0.f, 0.f};

    uint4 pa0, pa1, pb0, pb1, pb2, pb3;
#define LOAD_AB(k0)                                                     \
    {                                                                   \
        const ushort_t* sA = A + (size_t)(rb0 + sr) * 256 + (k0) + kh;  \
        pa0 = *(const uint4*)(sA);                                      \
        pa1 = *(const uint4*)(sA + 8);                                  \
        const ushort_t* sB = Wt + (size_t)sc * 256 + (k0) + kb;         \
        pb0 = *(const uint4*)(sB);                                      \
        pb1 = *(const uint4*)(sB + 8);                                  \
        pb2 = *(const uint4*)(sB + 16);                                 \
        pb3 = *(const uint4*)(sB + 24);                                 \
    }

    LOAD_AB(0);
#pragma unroll
    for (int t = 0; t < 4; ++t) {
        if (t) __syncthreads();
        *(uint4*)(&As[sr * 72 + kh]) = pa0;
        *(uint4*)(&As[sr * 72 + kh + 8]) = pa1;
        *(uint4*)(&Bs[sc * 72 + kb]) = pb0;
        *(uint4*)(&Bs[sc * 72 + kb + 8]) = pb1;
        *(uint4*)(&Bs[sc * 72 + kb + 16]) = pb2;
        *(uint4*)(&Bs[sc * 72 + kb + 24]) = pb3;
        __syncthreads();
        if (t < 3) LOAD_AB((t + 1) * 64);
#pragma unroll
        for (int ks = 0; ks < 2; ++ks) {
            const int ko = ks * 32 + qq * 8;
            bf16x8 a0 = *(const bf16x8*)&As[(wv * 16 + l15) * 72 + ko];
#pragma unroll
            for (int j = 0; j < 16; ++j) {
                bf16x8 b = *(const bf16x8*)&Bs[(j * 16 + l15) * 72 + ko];
                acc[j] = __builtin_amdgcn_mfma_f32_16x16x32_bf16(a0, b, acc[j], 0, 0, 0);
            }
        }
    }
#undef LOAD_AB

    // C/D: col = j*16 + l15, row = rb0 + wv*16 + qq*4 + v
    float bvz[8], bvr[8];
#pragma unroll
    for (int j = 0; j < 8; ++j) {
        bvz[j] = bz[j * 16 + l15];
        bvr[j] = br[j * 16 + l15];
    }
#pragma unroll
    for (int j = 0; j < 8; ++j)
#pragma unroll
        for (int v = 0; v < 4; ++v) {
            int row = rb0 + wv * 16 + qq * 4 + v;
            z_out[(size_t)row * 128 + j * 16 + l15] = f2b(sigm(acc[j][v] + bvz[j]));
        }
#pragma unroll
    for (int j = 0; j < 8; ++j)
#pragma unroll
        for (int v = 0; v < 4; ++v) {
            int row = rb0 + wv * 16 + qq * 4 + v;
            int col = j * 16 + l15;
            float r = sigm(acc[j + 8][v] + bvr[j]);
            float hh = h_prev[(size_t)row * 128 + col];
            rh_out[(size_t)row * 128 + col] = f2b(r * hh);
        }
}

// ---------------- gemm_c: 128x128 tile, K=256, tanh+GRU+LayerNorm -> out f32 ------

__global__ __launch_bounds__(512) void gemm_c(
    const ushort_t* __restrict__ A, const ushort_t* __restrict__ Wt,
    const float* __restrict__ bc, const float* __restrict__ h_prev,
    const ushort_t* __restrict__ z_in, const float* __restrict__ gamma,
    const float* __restrict__ beta, float* __restrict__ f_out) {
    __shared__ __align__(16) ushort_t As[128 * 72];
    __shared__ __align__(16) ushort_t Bs[128 * 72];
    const int tid = threadIdx.x;
    const int rb0 = blockIdx.x * 128;
    const int wv = tid >> 6, lane = tid & 63;
    const int l15 = lane & 15, qq = lane >> 4;
    const int sr = tid >> 2;
    const int kh = (tid & 3) * 16;

    floatx4 acc[8];
#pragma unroll
    for (int j = 0; j < 8; ++j) acc[j] = (floatx4){0.f, 0.f, 0.f, 0.f};

    uint4 pa0, pa1, pb0, pb1;
#define LOAD_AB(k0)                                                     \
    {                                                                   \
        const ushort_t* sA = A + (size_t)(rb0 + sr) * 256 + (k0) + kh;  \
        pa0 = *(const uint4*)(sA);                                      \
        pa1 = *(const uint4*)(sA + 8);                                  \
        const ushort_t* sB = Wt + (size_t)sr * 256 + (k0) + kh;         \
        pb0 = *(const uint4*)(sB);                                      \
        pb1 = *(const uint4*)(sB + 8);                                  \
    }

    LOAD_AB(0);
#pragma unroll
    for (int t = 0; t < 4; ++t) {
        if (t) __syncthreads();
        *(uint4*)(&As[sr * 72 + kh]) = pa0;
        *(uint4*)(&As[sr * 72 + kh + 8]) = pa1;
        *(uint4*)(&Bs[sr * 72 + kh]) = pb0;
        *(uint4*)(&Bs[sr * 72 + kh + 8]) = pb1;
        __syncthreads();
        if (t < 3) LOAD_AB((t + 1) * 64);
#pragma unroll
        for (int ks = 0; ks < 2; ++ks) {
            const int ko = ks * 32 + qq * 8;
            bf16x8 a0 = *(const bf16x8*)&As[(wv * 16 + l15) * 72 + ko];
#pragma unroll
            for (int j = 0; j < 8; ++j) {
                bf16x8 b = *(const bf16x8*)&Bs[(j * 16 + l15) * 72 + ko];
                acc[j] = __builtin_amdgcn_mfma_f32_16x16x32_bf16(a0, b, acc[j], 0, 0, 0);
            }
        }
    }
#undef LOAD_AB

    float bv[8], gv[8], bev[8];
#pragma unroll
    for (int j = 0; j < 8; ++j) {
        bv[j] = bc[j * 16 + l15];
        gv[j] = gamma[j * 16 + l15];
        bev[j] = beta[j * 16 + l15];
    }
#pragma unroll
    for (int v = 0; v < 4; ++v) {
        const int row = rb0 + wv * 16 + qq * 4 + v;
        float hn[8];
        float s = 0.f;
#pragma unroll
        for (int j = 0; j < 8; ++j) {
            float hc = tanh_fast(acc[j][v] + bv[j]);
            float zz = b2f((uint_t)z_in[(size_t)row * 128 + j * 16 + l15]);
            float hh = h_prev[(size_t)row * 128 + j * 16 + l15];
            hn[j] = (1.0f - zz) * hh + zz * hc;
            s += hn[j];
        }
#pragma unroll
        for (int o = 8; o > 0; o >>= 1) s += __shfl_xor(s, o);  // 16-lane quad
        float mu = s * (1.0f / 128.0f);
        float vv = 0.f;
#pragma unroll
        for (int j = 0; j < 8; ++j) {
            float d = hn[j] - mu;
            vv += d * d;
        }
#pragma unroll
        for (int o = 8; o > 0; o >>= 1) vv += __shfl_xor(vv, o);
        float inv = rsqrtf(vv * (1.0f / 128.0f) + LN_EPS);
#pragma unroll
        for (int j = 0; j < 8; ++j)
            f_out[(size_t)row * 128 + j * 16 + l15] =
                (hn[j] - mu) * inv * gv[j] + bev[j];
    }
}

// ---------------- launch ----------------

extern "C" void kernel_launch(void* const* d_in, const int* in_sizes, int n_in,
                              void* d_out, int out_size, void* d_ws, size_t ws_size,
                              hipStream_t stream) {
    const float* x = (const float*)d_in[0];
    const int* ei = (const int*)d_in[1];
    const float* h = (const float*)d_in[2];
    const float* Wz = (const float*)d_in[3];
    const float* bz = (const float*)d_in[4];
    const float* Wr = (const float*)d_in[5];
    const float* br = (const float*)d_in[6];
    const float* Wc = (const float*)d_in[7];
    const float* bcv = (const float*)d_in[8];
    const float* gamma = (const float*)d_in[9];
    const float* beta = (const float*)d_in[10];
    float* out = (float*)d_out;

    char* w = (char*)d_ws;
    int* offs = (int*)(w + 0);                     //    40,004 B
    float* dis = (float*)(w + 40960);              //    40,000 B
    int* csr_pk = (int*)(w + 81920);               //   640,000 B (w<<16|src packed)
    int* cnt = (int*)(w + 721920);                 //    40,000 B
    int* cursor = (int*)(w + 762880);              //    40,000 B
    int* bsum = (int*)(w + 803840);                //       160 B
    ushort_t* Wt_zr = (ushort_t*)(w + 1041920);    //   131,072 B
    ushort_t* Wt_c = (ushort_t*)(w + 1172992);     //    65,536 B
    ushort_t* xhb = (ushort_t*)(w + 1239040);      // 40,960,000 B [80000][256] x|h
    ushort_t* agg_xh = (ushort_t*)(w + 42199040);  // 40,960,000 B -> end 83,159,040
    // aliases (strict lifetime reuse on one stream):
    ushort_t* z_buf = (ushort_t*)(w + 1239040);   // xhb dead after gather16<0>
    ushort_t* rh_bf = (ushort_t*)(w + 21719040);  // second half of dead xhb

    hipMemsetAsync(cnt, 0, NN * sizeof(int), stream);
    // count_deg (625 blocks) | pack x,h -> interleaved bf16 + Wt transpose
    cp_k<<<11009, 256, 0, stream>>>(ei, cnt, x, h, xhb, Wz, Wr, Wc, Wt_zr, Wt_c);
    scan1<<<40, 256, 0, stream>>>(cnt, offs, bsum);
    scan3<<<40, 256, 0, stream>>>(cnt, bsum, offs, cursor, dis);
    fill_csr<<<EE / 256, 256, 0, stream>>>(ei, cursor, dis, csr_pk);

    // agg_xh (both halves) in one fused pass: one addr per edge serves x and h
    gather16<0><<<(NN / 16) * 8, 256, 0, stream>>>(xhb, offs, csr_pk, dis, agg_xh);
    // z and rh from ONE GEMM pass over agg_xh (A staged once, 256 output cols)
    gemm_zr<<<80000 / 128, 512, 0, stream>>>(agg_xh, Wt_zr, bz, br, h, z_buf, rh_bf);
    // rh aggregation into the h-half of agg_xh (x-half preserved)
    gather16<1><<<(NN / 16) * 8, 256, 0, stream>>>(rh_bf, offs, csr_pk, dis, agg_xh);
    // out = LN(GRU(tanh([agg_x|agg_rh]@Wc + bc)))
    gemm_c<<<80000 / 128, 512, 0, stream>>>(agg_xh, Wt_c, bcv, h, z_buf, gamma, beta,
                                            out);
}

// Round 11
// 287.287 us; speedup vs baseline: 1.0387x; 1.0387x over previous
//
#include <hip/hip_runtime.h>

#define NN 10000
#define BB 8
#define EE 160000
#define DH 128
#define LN_EPS 1e-5f

typedef unsigned short ushort_t;
typedef unsigned int uint_t;

typedef __bf16 bf16x8 __attribute__((ext_vector_type(8)));
typedef float floatx4 __attribute__((ext_vector_type(4)));
typedef float floatx2 __attribute__((ext_vector_type(2)));

__device__ __forceinline__ float b2f(uint_t u) { return __uint_as_float(u << 16); }
__device__ __forceinline__ ushort_t f2b(float f) {
    uint_t u = __float_as_uint(f);
    return (ushort_t)((u + 0x7fffu + ((u >> 16) & 1u)) >> 16);
}
__device__ __forceinline__ uint_t pack2(float lo, float hi) {
    return (uint_t)f2b(lo) | ((uint_t)f2b(hi) << 16);
}
__device__ __forceinline__ float sigm(float x) { return 1.0f / (1.0f + __expf(-x)); }
__device__ __forceinline__ float tanh_fast(float x) {
    float ex = __expf(2.0f * x);
    return 1.0f - 2.0f / (ex + 1.0f);
}

// unpack u32 holding 2 bf16 -> float2
__device__ __forceinline__ floatx2 unpk(uint_t u) {
    floatx2 r;
    r.x = __uint_as_float(u << 16);
    r.y = __uint_as_float(u & 0xffff0000u);
    return r;
}
// packed dual-FMA: a += w * v  (one VALU inst per 2 floats)
__device__ __forceinline__ void pk_fma(floatx2& a, floatx2 w, floatx2 v) {
    asm("v_pk_fma_f32 %0, %1, %2, %0" : "+v"(a) : "v"(w), "v"(v));
}
// accumulate 8 bf16 (uint4) with packed weight w2: 8 unpack + 4 pk_fma
__device__ __forceinline__ void acc8p(floatx2* a, floatx2 w2, uint4 v) {
    pk_fma(a[0], w2, unpk(v.x));
    pk_fma(a[1], w2, unpk(v.y));
    pk_fma(a[2], w2, unpk(v.z));
    pk_fma(a[3], w2, unpk(v.w));
}

// ---------------- CSR build ----------------

__global__ __launch_bounds__(256) void scan1(const int* __restrict__ cnt,
                                             int* __restrict__ offs,
                                             int* __restrict__ bsum) {
    __shared__ int s[256];
    const int t = threadIdx.x, idx = blockIdx.x * 256 + t;
    int x = (idx < NN) ? cnt[idx] : 0;
    s[t] = x;
    __syncthreads();
    for (int o = 1; o < 256; o <<= 1) {
        int v = s[t];
        int u = (t >= o) ? s[t - o] : 0;
        __syncthreads();
        s[t] = v + u;
        __syncthreads();
    }
    if (idx < NN) offs[idx] = s[t] - x;  // block-local exclusive
    if (t == 255) bsum[blockIdx.x] = s[255];
}

// scan3 also does the cross-block prefix (scan2 fused away)
__global__ __launch_bounds__(256) void scan3(const int* __restrict__ cnt,
                                             const int* __restrict__ bsum,
                                             int* __restrict__ offs,
                                             int* __restrict__ cursor,
                                             float* __restrict__ dis) {
    __shared__ int sb[40];
    __shared__ int pfx;
    const int t = threadIdx.x;
    if (t < 40) sb[t] = bsum[t];
    __syncthreads();
    if (t == 0) {
        int a = 0;
        for (int i = 0; i < blockIdx.x; ++i) a += sb[i];
        pfx = a;
    }
    __syncthreads();
    const int idx = blockIdx.x * 256 + t;
    if (idx < NN) {
        int off = offs[idx] + pfx;
        offs[idx] = off;
        cursor[idx] = off;
        dis[idx] = rsqrtf((float)(cnt[idx] + 1));
    }
    if (idx == 0) offs[NN] = EE;
}

// csr packed: bf16(dis[src])<<16 | src   (src < 16384 fits 14 bits)
__global__ void fill_csr(const int* __restrict__ ei, int* __restrict__ cursor,
                         const float* __restrict__ dis, int* __restrict__ csr_pk) {
    int e = blockIdx.x * 256 + threadIdx.x;
    if (e < EE) {
        int s = ei[e];
        int d = ei[EE + e];
        int pos = atomicAdd(&cursor[d], 1);
        csr_pk[pos] = (int)(((uint_t)f2b(dis[s]) << 16) | (uint_t)s);
    }
}

// ---------------- merged: count_deg | pack x,h interleaved + Wt transpose ---------
// xhb layout: [b*NN+n][256] with x in cols 0..127, h in cols 128..255.

__global__ __launch_bounds__(256) void cp_k(const int* __restrict__ ei,
                                            int* __restrict__ cnt,
                                            const float* __restrict__ x,
                                            const float* __restrict__ h,
                                            ushort_t* __restrict__ xhb,
                                            const float* __restrict__ Wz,
                                            const float* __restrict__ Wr,
                                            const float* __restrict__ Wc,
                                            ushort_t* __restrict__ Wt_zr,
                                            ushort_t* __restrict__ Wt_c) {
    if (blockIdx.x < 625) {  // count_deg: 625*256 = 160000 = EE
        int e = blockIdx.x * 256 + threadIdx.x;
        atomicAdd(&cnt[ei[EE + e]], 1);
        return;
    }
    const int bid = blockIdx.x - 625;
    if (bid < 10000) {
        const size_t o = ((size_t)bid * 256 + threadIdx.x) * 4;  // elem idx
        const size_t row = o >> 7, col = o & 127;
        float4 vx = *(const float4*)(x + o);
        uint2 px;
        px.x = pack2(vx.x, vx.y);
        px.y = pack2(vx.z, vx.w);
        *(uint2*)(xhb + row * 256 + col) = px;
        float4 vh = *(const float4*)(h + o);
        uint2 ph;
        ph.x = pack2(vh.x, vh.y);
        ph.y = pack2(vh.z, vh.w);
        *(uint2*)(xhb + row * 256 + 128 + col) = ph;
    } else {
        const int col = bid - 10000, k = threadIdx.x;
        if (col < 256) {
            float v = (col < 128) ? Wz[(size_t)k * 128 + col]
                                  : Wr[(size_t)k * 128 + col - 128];
            Wt_zr[(size_t)col * 256 + k] = f2b(v);
        } else {
            int c2 = col - 256;
            Wt_c[(size_t)c2 * 256 + k] = f2b(Wc[(size_t)k * 128 + c2]);
        }
    }
}

// ---------------- gather16: 4 waves x 4 nodes/wave, 16 lanes per node -------------
// dst[b,n] = dis[n] * ( sum_e dis[s]*src[b,s] + dis[n]*src[b,n] )
// MODE 0 (xh pass): src = xhb [b][n][256]; one addr per edge serves BOTH halves
// (h-load = x-load + 128, folded into the load's immediate offset). Writes both
// halves of agg_xh. MODE 1 (rh pass): src = rh_bf [b][n][128]; writes only the
// h-half of agg_xh (cols 128..255), preserving the x-half for the second GEMM.
// b = blockIdx&7 keeps XCD/L2 batch sharding. Packed CSR word -> ONE bpermute
// per edge; junk slots broadcast 0 -> weight 0.0 -> no predication.

template <int MODE>
__global__ __launch_bounds__(256) void gather16(
    const ushort_t* __restrict__ src, const int* __restrict__ offs,
    const int* __restrict__ csr_pk, const float* __restrict__ dis,
    ushort_t* __restrict__ dst) {
    const int tid = threadIdx.x, lane = tid & 63;
    const int b = blockIdx.x & 7;
    const int g = lane >> 4, il = lane & 15;
    const int ng = (blockIdx.x >> 3) * 16 + (tid >> 6) * 4 + g;  // my group's node
    const uint_t SST = (MODE == 0) ? 256u : 128u;
    const ushort_t* base = src + (size_t)b * NN * SST;
    const uint_t cofs = (uint_t)il * 8u;

    floatx2 a0[4], a1[4];
#pragma unroll
    for (int j = 0; j < 4; ++j) {
        a0[j] = (floatx2){0.f, 0.f};
        a1[j] = (floatx2){0.f, 0.f};
    }

    const int e0 = offs[ng], e1 = offs[ng + 1];
    const float dn = dis[ng];

    {  // self row, weight dn inside the sum
        const floatx2 d2 = {dn, dn};
        const uint_t off = (uint_t)ng * SST + cofs;
        acc8p(a0, d2, *(const uint4*)(base + off));
        if (MODE == 0) acc8p(a1, d2, *(const uint4*)(base + off + 128));
    }

    // max degree over the wave's 4 groups -> uniform loop bound
    int mx = e1 - e0;
    mx = max(mx, __shfl_xor(mx, 16));
    mx = max(mx, __shfl_xor(mx, 32));
    const int dmax = __builtin_amdgcn_readfirstlane(mx);
    const int pbase = (lane & 48) << 2;  // bpermute byte base of group's lane 0

    for (int ibase = 0; ibase < dmax; ibase += 16) {
        // refill: lane il of group g holds packed edge e0+ibase+il (0 if past end)
        int pk = 0;
        const int pos = e0 + ibase + il;
        if (pos < e1) pk = csr_pk[pos];
        const int lim = (dmax - ibase) < 16 ? (dmax - ibase) : 16;

        // 8 edges per step: all metadata, then all loads, then all FMAs
#define PROC8(OFF)                                                                   \
    {                                                                                \
        int p[8];                                                                    \
        uint_t q[8];                                                                 \
        _Pragma("unroll") for (int k = 0; k < 8; ++k) p[k] =                         \
            __builtin_amdgcn_ds_bpermute(pbase + ((OFF) + k) * 4, pk);               \
        _Pragma("unroll") for (int k = 0; k < 8; ++k) q[k] =                         \
            (uint_t)(p[k] & 0xffff) * SST + cofs;                                    \
        uint4 v[8];                                                                  \
        _Pragma("unroll") for (int k = 0; k < 8; ++k) v[k] =                         \
            *(const uint4*)(base + q[k]);                                            \
        uint4 u[8];                                                                  \
        if (MODE == 0) {                                                             \
            _Pragma("unroll") for (int k = 0; k < 8; ++k) u[k] =                     \
                *(const uint4*)(base + q[k] + 128);                                  \
        }                                                                            \
        _Pragma("unroll") for (int k = 0; k < 8; ++k) {                              \
            const float f = __uint_as_float((uint_t)p[k] & 0xffff0000u);             \
            const floatx2 w2 = {f, f};                                               \
            acc8p(a0, w2, v[k]);                                                     \
            if (MODE == 0) acc8p(a1, w2, u[k]);                                      \
        }                                                                            \
    }
        PROC8(0);
        if (lim > 8) PROC8(8);
#undef PROC8
    }

    // lane-private result: scale by dn, pack, store (all 64 lanes)
    const size_t o = ((size_t)b * NN + ng) * 256 + cofs;
    uint4 st;
    st.x = pack2(a0[0].x * dn, a0[0].y * dn);
    st.y = pack2(a0[1].x * dn, a0[1].y * dn);
    st.z = pack2(a0[2].x * dn, a0[2].y * dn);
    st.w = pack2(a0[3].x * dn, a0[3].y * dn);
    if (MODE == 0) {
        *(uint4*)(dst + o) = st;  // x-half
        uint4 st1;
        st1.x = pack2(a1[0].x * dn, a1[0].y * dn);
        st1.y = pack2(a1[1].x * dn, a1[1].y * dn);
        st1.z = pack2(a1[2].x * dn, a1[2].y * dn);
        st1.w = pack2(a1[3].x * dn, a1[3].y * dn);
        *(uint4*)(dst + o + 128) = st1;  // h-half
    } else {
        *(uint4*)(dst + o + 128) = st;  // rh into h-half, x-half preserved
    }
}

// ---------------- gemm_zr: 128x128 tile, K=256, mode=blockIdx.y (0:z, 1:rh) -------
// acc[8] = 32 VGPR (round-10's fused acc[16] spilled: VGPR_Count 56 < 64 needed,
// +12 MB scratch WRITE). 512 threads / 8 waves, register-prefetch pipeline.

__global__ __launch_bounds__(512) void gemm_zr(
    const ushort_t* __restrict__ A, const ushort_t* __restrict__ Wt,
    const float* __restrict__ bz, const float* __restrict__ br,
    const float* __restrict__ h_prev, ushort_t* __restrict__ z_out,
    ushort_t* __restrict__ rh_out) {
    __shared__ __align__(16) ushort_t As[128 * 72];
    __shared__ __align__(16) ushort_t Bs[128 * 72];
    const int tid = threadIdx.x;
    const int rb0 = blockIdx.x * 128;
    const int mode = blockIdx.y;
    const int cb0 = mode * 128;  // row offset into Wt_zr's 256 out-cols
    const int wv = tid >> 6, lane = tid & 63;
    const int l15 = lane & 15, qq = lane >> 4;
    const int sr = tid >> 2;        // 0..127: A row / B col staged by this thread
    const int kh = (tid & 3) * 16;  // 16-element K chunk

    floatx4 acc[8];
#pragma unroll
    for (int j = 0; j < 8; ++j) acc[j] = (floatx4){0.f, 0.f, 0.f, 0.f};

    uint4 pa0, pa1, pb0, pb1;
#define LOAD_AB(k0)                                                           \
    {                                                                         \
        const ushort_t* sA = A + (size_t)(rb0 + sr) * 256 + (k0) + kh;        \
        pa0 = *(const uint4*)(sA);                                            \
        pa1 = *(const uint4*)(sA + 8);                                        \
        const ushort_t* sB = Wt + (size_t)(cb0 + sr) * 256 + (k0) + kh;       \
        pb0 = *(const uint4*)(sB);                                            \
        pb1 = *(const uint4*)(sB + 8);                                        \
    }

    LOAD_AB(0);
#pragma unroll
    for (int t = 0; t < 4; ++t) {
        if (t) __syncthreads();
        *(uint4*)(&As[sr * 72 + kh]) = pa0;
        *(uint4*)(&As[sr * 72 + kh + 8]) = pa1;
        *(uint4*)(&Bs[sr * 72 + kh]) = pb0;
        *(uint4*)(&Bs[sr * 72 + kh + 8]) = pb1;
        __syncthreads();
        if (t < 3) LOAD_AB((t + 1) * 64);
#pragma unroll
        for (int ks = 0; ks < 2; ++ks) {
            const int ko = ks * 32 + qq * 8;
            bf16x8 a0 = *(const bf16x8*)&As[(wv * 16 + l15) * 72 + ko];
#pragma unroll
            for (int j = 0; j < 8; ++j) {
                bf16x8 b = *(const bf16x8*)&Bs[(j * 16 + l15) * 72 + ko];
                acc[j] = __builtin_amdgcn_mfma_f32_16x16x32_bf16(a0, b, acc[j], 0, 0, 0);
            }
        }
    }
#undef LOAD_AB

    // C/D: col = j*16 + l15, row = rb0 + wv*16 + qq*4 + v
    if (mode == 0) {
        float bv[8];
#pragma unroll
        for (int j = 0; j < 8; ++j) bv[j] = bz[j * 16 + l15];
#pragma unroll
        for (int j = 0; j < 8; ++j)
#pragma unroll
            for (int v = 0; v < 4; ++v) {
                int row = rb0 + wv * 16 + qq * 4 + v;
                z_out[(size_t)row * 128 + j * 16 + l15] = f2b(sigm(acc[j][v] + bv[j]));
            }
    } else {
        float bv[8];
#pragma unroll
        for (int j = 0; j < 8; ++j) bv[j] = br[j * 16 + l15];
#pragma unroll
        for (int j = 0; j < 8; ++j)
#pragma unroll
            for (int v = 0; v < 4; ++v) {
                int row = rb0 + wv * 16 + qq * 4 + v;
                float r = sigm(acc[j][v] + bv[j]);
                float hh = h_prev[(size_t)row * 128 + j * 16 + l15];
                rh_out[(size_t)row * 128 + j * 16 + l15] = f2b(r * hh);
            }
    }
}

// ---------------- gemm_c: 128x128 tile, K=256, tanh+GRU+LayerNorm -> out f32 ------

__global__ __launch_bounds__(512) void gemm_c(
    const ushort_t* __restrict__ A, const ushort_t* __restrict__ Wt,
    const float* __restrict__ bc, const float* __restrict__ h_prev,
    const ushort_t* __restrict__ z_in, const float* __restrict__ gamma,
    const float* __restrict__ beta, float* __restrict__ f_out) {
    __shared__ __align__(16) ushort_t As[128 * 72];
    __shared__ __align__(16) ushort_t Bs[128 * 72];
    const int tid = threadIdx.x;
    const int rb0 = blockIdx.x * 128;
    const int wv = tid >> 6, lane = tid & 63;
    const int l15 = lane & 15, qq = lane >> 4;
    const int sr = tid >> 2;
    const int kh = (tid & 3) * 16;

    floatx4 acc[8];
#pragma unroll
    for (int j = 0; j < 8; ++j) acc[j] = (floatx4){0.f, 0.f, 0.f, 0.f};

    uint4 pa0, pa1, pb0, pb1;
#define LOAD_AB(k0)                                                     \
    {                                                                   \
        const ushort_t* sA = A + (size_t)(rb0 + sr) * 256 + (k0) + kh;  \
        pa0 = *(const uint4*)(sA);                                      \
        pa1 = *(const uint4*)(sA + 8);                                  \
        const ushort_t* sB = Wt + (size_t)sr * 256 + (k0) + kh;         \
        pb0 = *(const uint4*)(sB);                                      \
        pb1 = *(const uint4*)(sB + 8);                                  \
    }

    LOAD_AB(0);
#pragma unroll
    for (int t = 0; t < 4; ++t) {
        if (t) __syncthreads();
        *(uint4*)(&As[sr * 72 + kh]) = pa0;
        *(uint4*)(&As[sr * 72 + kh + 8]) = pa1;
        *(uint4*)(&Bs[sr * 72 + kh]) = pb0;
        *(uint4*)(&Bs[sr * 72 + kh + 8]) = pb1;
        __syncthreads();
        if (t < 3) LOAD_AB((t + 1) * 64);
#pragma unroll
        for (int ks = 0; ks < 2; ++ks) {
            const int ko = ks * 32 + qq * 8;
            bf16x8 a0 = *(const bf16x8*)&As[(wv * 16 + l15) * 72 + ko];
#pragma unroll
            for (int j = 0; j < 8; ++j) {
                bf16x8 b = *(const bf16x8*)&Bs[(j * 16 + l15) * 72 + ko];
                acc[j] = __builtin_amdgcn_mfma_f32_16x16x32_bf16(a0, b, acc[j], 0, 0, 0);
            }
        }
    }
#undef LOAD_AB

    float bv[8], gv[8], bev[8];
#pragma unroll
    for (int j = 0; j < 8; ++j) {
        bv[j] = bc[j * 16 + l15];
        gv[j] = gamma[j * 16 + l15];
        bev[j] = beta[j * 16 + l15];
    }
#pragma unroll
    for (int v = 0; v < 4; ++v) {
        const int row = rb0 + wv * 16 + qq * 4 + v;
        float hn[8];
        float s = 0.f;
#pragma unroll
        for (int j = 0; j < 8; ++j) {
            float hc = tanh_fast(acc[j][v] + bv[j]);
            float zz = b2f((uint_t)z_in[(size_t)row * 128 + j * 16 + l15]);
            float hh = h_prev[(size_t)row * 128 + j * 16 + l15];
            hn[j] = (1.0f - zz) * hh + zz * hc;
            s += hn[j];
        }
#pragma unroll
        for (int o = 8; o > 0; o >>= 1) s += __shfl_xor(s, o);  // 16-lane quad
        float mu = s * (1.0f / 128.0f);
        float vv = 0.f;
#pragma unroll
        for (int j = 0; j < 8; ++j) {
            float d = hn[j] - mu;
            vv += d * d;
        }
#pragma unroll
        for (int o = 8; o > 0; o >>= 1) vv += __shfl_xor(vv, o);
        float inv = rsqrtf(vv * (1.0f / 128.0f) + LN_EPS);
#pragma unroll
        for (int j = 0; j < 8; ++j)
            f_out[(size_t)row * 128 + j * 16 + l15] =
                (hn[j] - mu) * inv * gv[j] + bev[j];
    }
}

// ---------------- launch ----------------

extern "C" void kernel_launch(void* const* d_in, const int* in_sizes, int n_in,
                              void* d_out, int out_size, void* d_ws, size_t ws_size,
                              hipStream_t stream) {
    const float* x = (const float*)d_in[0];
    const int* ei = (const int*)d_in[1];
    const float* h = (const float*)d_in[2];
    const float* Wz = (const float*)d_in[3];
    const float* bz = (const float*)d_in[4];
    const float* Wr = (const float*)d_in[5];
    const float* br = (const float*)d_in[6];
    const float* Wc = (const float*)d_in[7];
    const float* bcv = (const float*)d_in[8];
    const float* gamma = (const float*)d_in[9];
    const float* beta = (const float*)d_in[10];
    float* out = (float*)d_out;

    char* w = (char*)d_ws;
    int* offs = (int*)(w + 0);                     //    40,004 B
    float* dis = (float*)(w + 40960);              //    40,000 B
    int* csr_pk = (int*)(w + 81920);               //   640,000 B (w<<16|src packed)
    int* cnt = (int*)(w + 721920);                 //    40,000 B
    int* cursor = (int*)(w + 762880);              //    40,000 B
    int* bsum = (int*)(w + 803840);                //       160 B
    ushort_t* Wt_zr = (ushort_t*)(w + 1041920);    //   131,072 B
    ushort_t* Wt_c = (ushort_t*)(w + 1172992);     //    65,536 B
    ushort_t* xhb = (ushort_t*)(w + 1239040);      // 40,960,000 B [80000][256] x|h
    ushort_t* agg_xh = (ushort_t*)(w + 42199040);  // 40,960,000 B -> end 83,159,040
    // aliases (strict lifetime reuse on one stream):
    ushort_t* z_buf = (ushort_t*)(w + 1239040);   // xhb dead after gather16<0>
    ushort_t* rh_bf = (ushort_t*)(w + 21719040);  // second half of dead xhb

    hipMemsetAsync(cnt, 0, NN * sizeof(int), stream);
    // count_deg (625 blocks) | pack x,h -> interleaved bf16 + Wt transpose
    cp_k<<<11009, 256, 0, stream>>>(ei, cnt, x, h, xhb, Wz, Wr, Wc, Wt_zr, Wt_c);
    scan1<<<40, 256, 0, stream>>>(cnt, offs, bsum);
    scan3<<<40, 256, 0, stream>>>(cnt, bsum, offs, cursor, dis);
    fill_csr<<<EE / 256, 256, 0, stream>>>(ei, cursor, dis, csr_pk);

    // agg_xh (both halves) in one fused pass: one addr per edge serves x and h
    gather16<0><<<(NN / 16) * 8, 256, 0, stream>>>(xhb, offs, csr_pk, dis, agg_xh);
    // z (y=0) and rh (y=1), 128x128 tiles, acc[8] -> no spills
    gemm_zr<<<dim3(80000 / 128, 2), 512, 0, stream>>>(agg_xh, Wt_zr, bz, br, h,
                                                      z_buf, rh_bf);
    // rh aggregation into the h-half of agg_xh (x-half preserved)
    gather16<1><<<(NN / 16) * 8, 256, 0, stream>>>(rh_bf, offs, csr_pk, dis, agg_xh);
    // out = LN(GRU(tanh([agg_x|agg_rh]@Wc + bc)))
    gemm_c<<<80000 / 128, 512, 0, stream>>>(agg_xh, Wt_c, bcv, h, z_buf, gamma, beta,
                                            out);
}